// Round 7
// baseline (254.363 us; speedup 1.0000x reference)
//
#include <hip/hip_runtime.h>

// ---------------------------------------------------------------------------
// IntegerCifar10Net: 4-bit quantized CNN, B=512.
// Post-layer-1 math is EXACT integer arithmetic (acts 0..7, weights -7..7,
// partial sums < 2^31) -> i8 MFMA (mfma_i32_16x16x64_i8, exact i32 accum).
// Layer 1 stays fp64 (continuous input; matches ref quant decisions).
//
// Round-10 changes (conv1 stall-bound at 42%; stalls track LDS footprint):
//  * conv1: xs/wd staged in LDS as FP32 (raw input floats; i8 weights as
//    float). cvt to double at use is EXACT (fp32->fp64 lossless, ints<=7
//    lossless) -> every fp64 FMA sees identical operands -> bit-exact.
//    LDS 30.2 -> 19.2 KB; xs reads as float2 (bank-pair stride 1, clean).
//  * prep: ALL weight quantization in fp32 -- rintf(clip(w)*7) is exactly
//    the reference's own jnp.round(clip(w)*7) fp32 sequence (half-even),
//    bit-identical by construction; removes every fp64 chain from prep.
// Inter-layer activations: plane-blocked u8 [img][c/16][px][16] (value=7*act).
// ---------------------------------------------------------------------------

typedef __attribute__((ext_vector_type(4))) int v4i;

#if defined(__has_builtin)
# if __has_builtin(__builtin_amdgcn_sdot4)
#  define HAS_SDOT4 1
# endif
#endif

__device__ __forceinline__ int dot4_i8(int a, int b, int c) {
#ifdef HAS_SDOT4
    return __builtin_amdgcn_sdot4(a, b, c, false);
#else
    c += ((a      ) & 0xff) * (int)(signed char)(b      );
    c += ((a >>  8) & 0xff) * (int)(signed char)(b >>  8);
    c += ((a >> 16) & 0xff) * (int)(signed char)(b >> 16);
    c += ((a >> 24) & 0xff) * (int)(signed char)(b >> 24);
    return c;
#endif
}

// global->LDS 16B DMA (dest must be wave-uniform base + lane*16)
__device__ __forceinline__ void gld_lds16(const void* g, void* l) {
    __builtin_amdgcn_global_load_lds(
        (const __attribute__((address_space(1))) unsigned int*)g,
        (__attribute__((address_space(3))) unsigned int*)l, 16, 0, 0);
}

// workspace offsets (bytes)
#define O_QW1    0u          // 1728    i8 conv1 [64][3][9]
#define O_QWF2   4096u       // 5120    i8 fc2   [10][512]
#define O_ZERO   10240u      // 256     zero scratch for OOB DMA source
#define O_QWT2   16384u      // 36864   i8 [1grp][1pass][4][576][16]
#define O_QWT3   65536u      // 73728   i8 [2grp][1pass][4][576][16]
#define O_QWT4   147456u     // 147456  i8 [2grp][2pass][4][576][16]
#define O_QWT5   294912u     // 294912  i8 [4grp][2pass][4][576][16]
#define O_QWT6   589824u     // 589824  i8 [4grp][4pass][4][576][16]
#define O_QWF1   1179648u    // 2097152 i8 [512][4096] k in plane-blocked order
#define O_BUFA   3276800u    // 33.5 MB
#define O_BUFB   36831232u   // 8.4 MB  (total ~45.2 MB)

// ---------------------------------------------------------------------------
// fused weight prep: one launch, segment-dispatched by blockIdx.x
// fp32 quant == reference's exact op sequence (round-half-even).
// ---------------------------------------------------------------------------
__device__ __forceinline__ signed char quant_wf(float v) {
    return (signed char)(int)rintf(fminf(fmaxf(v, -1.0f), 1.0f) * 7.0f);
}

__device__ __forceinline__ void quantw_body(const float* __restrict__ w,
                                            signed char* __restrict__ q, int i, int n) {
    if (i < n) q[i] = quant_wf(w[i]);
}

// conv weights: fp32 [CO][CI][3][3] -> i8 LDS-image layout
// [grp][pass][c][row=co_l*9+tap][b], co=grp*64+co_l, ci=pass*64+c*16+b
__device__ __forceinline__ void quantw_t8p_body(const float* __restrict__ w,
                                                signed char* __restrict__ o,
                                                int CI, int i, int n) {
    if (i < n) {
        const int b  = i & 15;
        const int t  = i >> 4;              // 16B-chunk index
        const int rows_per_grp = CI * 36;   // (CI/64)*2304
        const int grp  = t / rows_per_grp;
        int rr = t - grp * rows_per_grp;
        const int pass = rr / 2304;
        rr -= pass * 2304;
        const int c    = rr / 576;
        const int row  = rr - c * 576;
        const int co_l = row / 9;
        const int tap  = row - co_l * 9;
        const int co = grp * 64 + co_l;
        const int ci = pass * 64 + c * 16 + b;
        o[i] = quant_wf(w[(co * CI + ci) * 9 + tap]);
    }
}

// fc1 weights, one block per row: fp32 [512][4096 nchw-k] -> i8 plane-blocked
// out kn = gp*256 + px*16 + b  maps to  nchw ko = (gp*16+b)*16 + px.
__device__ __forceinline__ void quantw_fc1_row(const float* __restrict__ w,
                                               signed char* __restrict__ o,
                                               int row, int tid,
                                               unsigned char* __restrict__ sb)
{
    const float4* wr = (const float4*)(w + row * 4096);
    unsigned int* so = (unsigned int*)sb;
#pragma unroll
    for (int k = 0; k < 4; ++k) {
        const int d = k * 256 + tid;           // dword index 0..1023
        float4 v = wr[d];
        unsigned int pk =
              ((unsigned int)(unsigned char)quant_wf(v.x))
            | ((unsigned int)(unsigned char)quant_wf(v.y) << 8)
            | ((unsigned int)(unsigned char)quant_wf(v.z) << 16)
            | ((unsigned int)(unsigned char)quant_wf(v.w) << 24);
        so[d] = pk;
    }
    __syncthreads();
    unsigned int* og = (unsigned int*)(o + row * 4096);
#pragma unroll
    for (int k = 0; k < 4; ++k) {
        const int od = k * 256 + tid;
        unsigned int pk = 0;
#pragma unroll
        for (int u = 0; u < 4; ++u) {
            const int kn = od * 4 + u;
            const int gp = kn >> 8, r = kn & 255;
            const int px = r >> 4, b = r & 15;
            const int ko = (gp * 16 + b) * 16 + px;
            pk |= (unsigned int)sb[ko] << (8 * u);
        }
        og[od] = pk;
    }
}

// block ranges: [0,7) qw1 | [7,27) qwf2 | [27,171) qwt2 | [171,459) qwt3 |
// [459,1035) qwt4 | [1035,2187) qwt5 | [2187,4491) qwt6 | [4491,5003) qwf1
__global__ __launch_bounds__(256) void prep_k(
    const float* __restrict__ w1,  signed char* __restrict__ qw1,
    const float* __restrict__ wf2, signed char* __restrict__ qwf2,
    const float* __restrict__ w2,  signed char* __restrict__ qwt2,
    const float* __restrict__ w3,  signed char* __restrict__ qwt3,
    const float* __restrict__ w4,  signed char* __restrict__ qwt4,
    const float* __restrict__ w5,  signed char* __restrict__ qwt5,
    const float* __restrict__ w6,  signed char* __restrict__ qwt6,
    const float* __restrict__ wf1, signed char* __restrict__ qwf1,
    unsigned char* __restrict__ zs)
{
    __shared__ __align__(16) unsigned char sb[4096];
    const int blk = blockIdx.x;
    const int t   = threadIdx.x;
    if (blk == 0 && t < 16) ((int4*)zs)[t] = int4{0, 0, 0, 0};
    if      (blk < 7)    quantw_body(w1, qw1, blk * 256 + t, 1728);
    else if (blk < 27)   quantw_body(wf2, qwf2, (blk - 7) * 256 + t, 5120);
    else if (blk < 171)  quantw_t8p_body(w2, qwt2, 64,  (blk - 27)   * 256 + t, 36864);
    else if (blk < 459)  quantw_t8p_body(w3, qwt3, 64,  (blk - 171)  * 256 + t, 73728);
    else if (blk < 1035) quantw_t8p_body(w4, qwt4, 128, (blk - 459)  * 256 + t, 147456);
    else if (blk < 2187) quantw_t8p_body(w5, qwt5, 128, (blk - 1035) * 256 + t, 294912);
    else if (blk < 4491) quantw_t8p_body(w6, qwt6, 256, (blk - 2187) * 256 + t, 589824);
    else                 quantw_fc1_row(wf1, qwf1, blk - 4491, t, sb);
}

// ---------------------------------------------------------------------------
// conv1: 3->64, 32x32, fp64-exact math with FP32 LDS staging (exact cvt at
// use). Output: plane-blocked [img][4][1024][16]. One block per (img,slab);
// cog loop computes 16 co at a time; ob ping-pong; contiguous 4KB stores.
// ---------------------------------------------------------------------------
#define XSTR 34
#define XPL  (10 * XSTR)
__global__ __launch_bounds__(256) void conv1_k(
    const float* __restrict__ x, const signed char* __restrict__ wq,
    const float* __restrict__ gvec, const float* __restrict__ bvec,
    unsigned char* __restrict__ out)
{
    __shared__ __align__(16) float xs[3 * XPL];  // 4080 B
    __shared__ __align__(16) float wd[64 * 27];  // 6912 B
    __shared__ __align__(16) unsigned char ob[2][256 * 16];  // ping-pong 8 KB

    const int tid  = threadIdx.x;
    const int sp   = tid & 63;
    const int cg   = tid >> 6;
    const int img  = blockIdx.x >> 2;
    const int slab = blockIdx.x & 3;
    const int y0s  = slab * 8;
    const int yb = sp >> 4, xb = sp & 15;
    const int ysl = yb * 2, x0 = xb * 2;

    for (int i = tid; i < 1728; i += 256)
        wd[i] = (float)wq[i];
    for (int i = tid; i < 3 * XPL; i += 256) {
        int ci = i / XPL, r = i - ci * XPL;
        int ry = r / XSTR, rx = r - ry * XSTR;
        int gy = y0s - 1 + ry, gx = rx - 1;
        float v = 0.0f;
        if ((unsigned)gy < 32u && (unsigned)gx < 32u)
            v = x[(img * 3 + ci) * 1024 + gy * 32 + gx];
        xs[i] = v;
    }
    __syncthreads();

    for (int cog = 0; cog < 4; ++cog) {
        double acc[4][4];
#pragma unroll
        for (int l = 0; l < 4; ++l)
#pragma unroll
            for (int p = 0; p < 4; ++p) acc[l][p] = 0.0;

#pragma unroll
        for (int ci = 0; ci < 3; ++ci) {
            double a[4][4];
#pragma unroll
            for (int iy = 0; iy < 4; ++iy) {
                const float2* xr = (const float2*)&xs[ci * XPL + (ysl + iy) * XSTR];
                float2 p0 = xr[xb], p1 = xr[xb + 1];
                a[iy][0] = (double)p0.x; a[iy][1] = (double)p0.y;
                a[iy][2] = (double)p1.x; a[iy][3] = (double)p1.y;
            }
#pragma unroll
            for (int l = 0; l < 4; ++l) {
                const float* wr = &wd[((cog * 16 + cg * 4 + l) * 3 + ci) * 9];
#pragma unroll
                for (int ky = 0; ky < 3; ++ky)
#pragma unroll
                    for (int kx = 0; kx < 3; ++kx) {
                        const double wv = (double)wr[ky * 3 + kx];
                        acc[l][0] = fma(wv, a[ky    ][kx    ], acc[l][0]);
                        acc[l][1] = fma(wv, a[ky    ][kx + 1], acc[l][1]);
                        acc[l][2] = fma(wv, a[ky + 1][kx    ], acc[l][2]);
                        acc[l][3] = fma(wv, a[ky + 1][kx + 1], acc[l][3]);
                    }
            }
        }

        // epilogue: 7*y = acc*g + 7*b; q = clamp(rint(7y), 0, 7)
        int qv[4][4];
#pragma unroll
        for (int l = 0; l < 4; ++l) {
            const int co = cog * 16 + cg * 4 + l;
            const double gg  = (double)gvec[co];
            const double bb7 = (double)bvec[co] * 7.0;
#pragma unroll
            for (int p = 0; p < 4; ++p) {
                int qi = (int)rint(fma(acc[l][p], gg, bb7));
                qv[l][p] = qi < 0 ? 0 : (qi > 7 ? 7 : qi);
            }
        }
#pragma unroll
        for (int p = 0; p < 4; ++p) {
            unsigned int wv = (unsigned int)qv[0][p]
                            | ((unsigned int)qv[1][p] << 8)
                            | ((unsigned int)qv[2][p] << 16)
                            | ((unsigned int)qv[3][p] << 24);
            const int r = ysl + (p >> 1), c = x0 + (p & 1);
            const int px = r * 32 + c;
            const int slot = (cg ^ ((px >> 3) & 3) ^ ((px >> 6) & 3)) & 3;
            *(unsigned int*)&ob[cog & 1][px * 16 + slot * 4] = wv;
        }
        __syncthreads();
        {
            uint4 d = *(const uint4*)&ob[cog & 1][tid * 16];
            const int s = (((tid >> 3) & 3) ^ ((tid >> 6) & 3)) & 3;
            unsigned e0 = d.x, e1 = d.y, e2 = d.z, e3 = d.w, t;
            if (s & 1) { t = e0; e0 = e1; e1 = t; t = e2; e2 = e3; e3 = t; }
            if (s & 2) { t = e0; e0 = e2; e2 = t; t = e1; e1 = e3; e3 = t; }
            uint4 o; o.x = e0; o.y = e1; o.z = e2; o.w = e3;
            *(uint4*)&out[(size_t)img * 65536 + (size_t)cog * 16384
                          + y0s * 512 + tid * 16] = o;
        }
    }
}

// ---------------------------------------------------------------------------
// i8 MFMA implicit-GEMM conv: plane-blocked u8 in [img][CI/16][H*W][16],
// pre-permuted i8 weights, plane-blocked u8 out [img][CO/16][PXO][16].
// Block: 256 thr = 4 waves; 64 co x 256 px. K in ci-chunks of 64.
// All staging via global_load_lds width-16 DMA (lane-stride 16B = dense).
// TPB>1 (NPASS==1, IPB==1): persistent weights + DOUBLE-BUFFERED act tiles.
// Morton px->m: lane's 4 accs = 2x2 pool window.
// Epilogue: division-free fp64 affine; POOL maxes INTEGER accs first (g>0).
// ---------------------------------------------------------------------------
template<int CI, int CO, int H, int W, bool POOL, int IPB, int TPB>
__global__ __launch_bounds__(256, 2) void conv_i8_k(
    const unsigned char* __restrict__ in, const signed char* __restrict__ wt,
    const float* __restrict__ gvec, const float* __restrict__ bvec,
    unsigned char* __restrict__ out, const unsigned char* __restrict__ zs)
{
    constexpr int ATX    = (IPB == 1) ? 18 : 10;
    constexpr int APX    = ATX * ATX;
    constexpr int APLANE = IPB * APX * 16;       // bytes per act plane
    constexpr int AREG   = 4 * APLANE;           // one act buffer
    constexpr int NBUF   = (TPB > 1) ? 2 : 1;
    constexpr int WBASE  = NBUF * AREG;
    constexpr int WPLANE = 576 * 16;             // 64 co x 9 taps rows
    constexpr int NPASS  = CI / 64;
    constexpr int PIN    = CI / 16;              // input planes
    constexpr int PXI    = H * W;                // input px per img
    constexpr int POUT   = CO / 16;
    constexpr int PXO    = POOL ? (H / 2) * (W / 2) : H * W;
    static_assert(TPB == 1 || (NPASS == 1 && IPB == 1), "TPB>1 needs NPASS==1");

    __shared__ __align__(16) char lds[WBASE + 4 * WPLANE];

    const int tid = threadIdx.x;
    const int l   = tid & 63;
    const int w   = tid >> 6;
    const int n   = l & 15;
    const int q   = l >> 4;

    const int co_base = blockIdx.y * 64;
    const int wy8 = (IPB == 1) ? (w >> 1) * 8 : 0;
    const int wx8 = (IPB == 1) ? (w & 1) * 8 : 0;
    const int tilepx = (IPB == 4) ? w * APX : 0;

    const int ly = ((n >> 3) & 1) * 2 + ((n >> 1) & 1);
    const int lx = ((n >> 2) & 1) * 2 + (n & 1);

    int abase[4], wbase[4];
#pragma unroll
    for (int ps = 0; ps < 4; ++ps) {
        int ay0 = wy8 + (ps >> 1) * 4 + ly;
        int ax0 = wx8 + (ps & 1) * 4 + lx;
        abase[ps] = q * APLANE + (tilepx + ay0 * ATX + ax0) * 16;
    }
#pragma unroll
    for (int cs = 0; cs < 4; ++cs)
        wbase[cs] = WBASE + q * WPLANE + ((cs * 16 + n) * 9) * 16;

    // --- staging helpers (plane-blocked global layout) ---
    auto stage_act = [&](int boff, int img0, int regY0, int regX0, int pass) {
#pragma unroll
        for (int c = 0; c < 4; ++c) {
            const int gp = pass * 4 + c;
            for (int base = 0; base < IPB * APX; base += 256) {
                const int px_g = base + tid;
                if (px_g < IPB * APX) {
                    int tile = 0, px = px_g;
                    if (IPB == 4) { tile = px_g / APX; px = px_g - tile * APX; }
                    const int gy = regY0 - 1 + px / ATX;
                    const int gx = regX0 - 1 + px % ATX;
                    const int bimg = img0 + tile;
                    const void* src =
                        ((unsigned)gy < (unsigned)H && (unsigned)gx < (unsigned)W)
                        ? (const void*)&in[((size_t)(bimg * PIN + gp) * PXI + gy * W + gx) * 16]
                        : (const void*)zs;
                    gld_lds16(src, &lds[boff + c * APLANE + px_g * 16]);
                }
            }
        }
    };
    auto stage_w = [&](int pass) {
        const signed char* wsrc = wt + (size_t)(blockIdx.y * NPASS + pass) * (4 * WPLANE);
#pragma unroll
        for (int base = 0; base < 2304; base += 256)
            gld_lds16(wsrc + (base + tid) * 16, &lds[WBASE + (base + tid) * 16]);
    };
    auto taps = [&](v4i acc[4][4], int boff) {
#pragma unroll
        for (int tap = 0; tap < 9; ++tap) {
            const int toff = ((tap / 3) * ATX + (tap % 3)) * 16;
            v4i bf[4], af[4];
#pragma unroll
            for (int cs = 0; cs < 4; ++cs)
                bf[cs] = *(const v4i*)&lds[wbase[cs] + tap * 16];
#pragma unroll
            for (int ps = 0; ps < 4; ++ps)
                af[ps] = *(const v4i*)&lds[boff + abase[ps] + toff];
#pragma unroll
            for (int ps = 0; ps < 4; ++ps)
#pragma unroll
                for (int cs = 0; cs < 4; ++cs)
                    acc[ps][cs] = __builtin_amdgcn_mfma_i32_16x16x64_i8(
                        af[ps], bf[cs], acc[ps][cs], 0, 0, 0);
        }
    };
    auto epilogue = [&](v4i acc[4][4], int img0, int regY0, int regX0) {
        const int bimg = (IPB == 1) ? img0 : (img0 + w);
#pragma unroll
        for (int cs = 0; cs < 4; ++cs) {
            const int co = co_base + cs * 16 + n;
            const int pl = (co_base >> 4) + cs;
            const double g7 = (double)gvec[co] * (1.0 / 7.0);
            const double b7 = (double)bvec[co] * 7.0;
#pragma unroll
            for (int ps = 0; ps < 4; ++ps) {
                const int Yb = regY0 + wy8 + (ps >> 1) * 4 + (q >> 1) * 2;
                const int Xb = regX0 + wx8 + (ps & 1) * 4 + (q & 1) * 2;
                if (POOL) {
                    int ms = max(max(acc[ps][cs][0], acc[ps][cs][1]),
                                 max(acc[ps][cs][2], acc[ps][cs][3]));
                    int qi = (int)rint(fma((double)ms, g7, b7));
                    qi = qi < 0 ? 0 : (qi > 7 ? 7 : qi);
                    out[((size_t)(bimg * POUT + pl) * PXO + (Yb >> 1) * (W / 2) + (Xb >> 1)) * 16 + n]
                        = (unsigned char)qi;
                } else {
#pragma unroll
                    for (int r = 0; r < 4; ++r) {
                        int qi = (int)rint(fma((double)acc[ps][cs][r], g7, b7));
                        qi = qi < 0 ? 0 : (qi > 7 ? 7 : qi);
                        const int Y = Yb + (r >> 1), X = Xb + (r & 1);
                        out[((size_t)(bimg * POUT + pl) * PXO + Y * W + X) * 16 + n]
                            = (unsigned char)qi;
                    }
                }
            }
        }
    };

    if (TPB == 1) {
        // ---- pass loop, weights re-staged per pass ----
        int img = 0, regY0 = 0, regX0 = 0;
        if (IPB == 1) {
            constexpr int rpw = W / 16;
            constexpr int rpi = (H / 16) * rpw;
            img   = blockIdx.x / rpi;
            int r = blockIdx.x % rpi;
            regY0 = (r / rpw) * 16;
            regX0 = (r % rpw) * 16;
        } else {
            img = (int)blockIdx.x * 4;
        }
        v4i acc[4][4];
#pragma unroll
        for (int ps = 0; ps < 4; ++ps)
#pragma unroll
            for (int cs = 0; cs < 4; ++cs) acc[ps][cs] = (v4i)0;

        for (int pass = 0; pass < NPASS; ++pass) {
            __syncthreads();
            stage_act(0, img, regY0, regX0, pass);
            stage_w(pass);
            __syncthreads();
            taps(acc, 0);
        }
        epilogue(acc, img, regY0, regX0);
    } else {
        // ---- persistent weights + double-buffered act tile pipeline ----
        auto tilec = [&](int t, int& im, int& ry, int& rx) {
            if (H == 32) { im = t >> 2; ry = ((t >> 1) & 1) * 16; rx = (t & 1) * 16; }
            else         { im = t; ry = 0; rx = 0; }
        };
        stage_w(0);
        int im0, ry0, rx0;
        tilec((int)blockIdx.x * TPB, im0, ry0, rx0);
        stage_act(0, im0, ry0, rx0, 0);
        __syncthreads();
        for (int tt = 0; tt < TPB; ++tt) {
            int imc, ryc, rxc;
            tilec((int)blockIdx.x * TPB + tt, imc, ryc, rxc);
            if (tt + 1 < TPB) {
                int imn, ryn, rxn;
                tilec((int)blockIdx.x * TPB + tt + 1, imn, ryn, rxn);
                stage_act(((tt + 1) & 1) * AREG, imn, ryn, rxn, 0);
            }
            v4i acc[4][4];
#pragma unroll
            for (int ps = 0; ps < 4; ++ps)
#pragma unroll
                for (int cs = 0; cs < 4; ++cs) acc[ps][cs] = (v4i)0;
            taps(acc, (tt & 1) * AREG);
            epilogue(acc, imc, ryc, rxc);
            __syncthreads();   // drains tile t+1's DMA; WAR-safe buffer reuse
        }
    }
}

// ---------------------------------------------------------------------------
// FC1: h[512][4096] u8 x wt[512][4096] i8 -> u8 [512][512], i8 MFMA,
// 32x32 output tile, 4 waves split K=4096 into 1024 each, LDS reduce.
// ---------------------------------------------------------------------------
__global__ __launch_bounds__(256, 2) void fc1_i8_k(
    const unsigned char* __restrict__ h, const signed char* __restrict__ wt,
    const float* __restrict__ gvec, const float* __restrict__ bvec,
    unsigned char* __restrict__ out)
{
    __shared__ int red[4096];
    const int tid = threadIdx.x;
    const int l = tid & 63, w = tid >> 6;
    const int n = l & 15, q = l >> 4;
    const int m0 = blockIdx.x * 32, n0 = blockIdx.y * 32;

    v4i acc[2][2];
#pragma unroll
    for (int a = 0; a < 2; ++a)
#pragma unroll
        for (int b = 0; b < 2; ++b) acc[a][b] = (v4i)0;

    const int kb = w * 1024;
    for (int ks = 0; ks < 16; ++ks) {
        const int k = kb + ks * 64 + q * 16;
        v4i af[2], bf[2];
#pragma unroll
        for (int ms = 0; ms < 2; ++ms)
            af[ms] = *(const v4i*)&h[(m0 + ms * 16 + n) * 4096 + k];
#pragma unroll
        for (int ns = 0; ns < 2; ++ns)
            bf[ns] = *(const v4i*)&wt[(n0 + ns * 16 + n) * 4096 + k];
#pragma unroll
        for (int ms = 0; ms < 2; ++ms)
#pragma unroll
            for (int ns = 0; ns < 2; ++ns)
                acc[ms][ns] = __builtin_amdgcn_mfma_i32_16x16x64_i8(
                    af[ms], bf[ns], acc[ms][ns], 0, 0, 0);
    }

#pragma unroll
    for (int ms = 0; ms < 2; ++ms)
#pragma unroll
        for (int ns = 0; ns < 2; ++ns)
#pragma unroll
            for (int r = 0; r < 4; ++r)
                red[w * 1024 + (ms * 16 + q * 4 + r) * 32 + ns * 16 + n] = acc[ms][ns][r];
    __syncthreads();

#pragma unroll
    for (int j = 0; j < 4; ++j) {
        const int e = tid * 4 + j;
        int s = red[e] + red[1024 + e] + red[2048 + e] + red[3072 + e];
        const int ml = e >> 5, nl = e & 31;
        const int co = n0 + nl;
        double y7 = fma((double)s, (double)gvec[co] * (1.0 / 7.0), (double)bvec[co] * 7.0);
        int qi = (int)rint(y7);
        qi = qi < 0 ? 0 : (qi > 7 ? 7 : qi);
        out[(m0 + ml) * 512 + co] = (unsigned char)qi;
    }
}

// FC2: vectorized int4 loads + dot4
__global__ __launch_bounds__(256) void fc2_k(
    const unsigned char* __restrict__ h, const signed char* __restrict__ wq,
    const float* __restrict__ gvec, const float* __restrict__ bvec,
    float* __restrict__ out)
{
    const int gid = blockIdx.x * 256 + threadIdx.x;
    const int b = gid >> 4;
    const int n = gid & 15;
    if (b >= 512 || n >= 10) return;
    const int* hp = (const int*)&h[b * 512];
    const int* wp = (const int*)&wq[n * 512];
    int s = 0;
#pragma unroll 4
    for (int k = 0; k < 128; k += 4) {
        int4 hv = *(const int4*)&hp[k];
        int4 wv = *(const int4*)&wp[k];
        s = dot4_i8(hv.x, wv.x, s);
        s = dot4_i8(hv.y, wv.y, s);
        s = dot4_i8(hv.z, wv.z, s);
        s = dot4_i8(hv.w, wv.w, s);
    }
    double y7 = fma((double)s, (double)gvec[n] * (1.0 / 7.0), (double)bvec[n] * 7.0);
    double r = rint(y7);
    r = fmin(fmax(r, -7.0), 7.0);
    out[b * 10 + n] = (float)(r / 7.0);
}

// ---------------------------------------------------------------------------
extern "C" void kernel_launch(void* const* d_in, const int* in_sizes, int n_in,
                              void* d_out, int out_size, void* d_ws, size_t ws_size,
                              hipStream_t stream) {
    const float* x   = (const float*)d_in[0];
    const float* w1  = (const float*)d_in[1];
    const float* g1  = (const float*)d_in[2];
    const float* b1  = (const float*)d_in[3];
    const float* w2  = (const float*)d_in[4];
    const float* g2  = (const float*)d_in[5];
    const float* b2  = (const float*)d_in[6];
    const float* w3  = (const float*)d_in[7];
    const float* g3  = (const float*)d_in[8];
    const float* b3  = (const float*)d_in[9];
    const float* w4  = (const float*)d_in[10];
    const float* g4  = (const float*)d_in[11];
    const float* b4  = (const float*)d_in[12];
    const float* w5  = (const float*)d_in[13];
    const float* g5  = (const float*)d_in[14];
    const float* b5  = (const float*)d_in[15];
    const float* w6  = (const float*)d_in[16];
    const float* g6  = (const float*)d_in[17];
    const float* b6  = (const float*)d_in[18];
    const float* wf1 = (const float*)d_in[19];
    const float* gf1 = (const float*)d_in[20];
    const float* bf1 = (const float*)d_in[21];
    const float* wf2 = (const float*)d_in[22];
    const float* gf2 = (const float*)d_in[23];
    const float* bf2 = (const float*)d_in[24];

    char* ws = (char*)d_ws;
    signed char*   qw1  = (signed char*)(ws + O_QW1);
    signed char*   qwf2 = (signed char*)(ws + O_QWF2);
    unsigned char* zs   = (unsigned char*)(ws + O_ZERO);
    signed char*   qwt2 = (signed char*)(ws + O_QWT2);
    signed char*   qwt3 = (signed char*)(ws + O_QWT3);
    signed char*   qwt4 = (signed char*)(ws + O_QWT4);
    signed char*   qwt5 = (signed char*)(ws + O_QWT5);
    signed char*   qwt6 = (signed char*)(ws + O_QWT6);
    signed char*   qwf1 = (signed char*)(ws + O_QWF1);
    unsigned char* bufA = (unsigned char*)(ws + O_BUFA);
    unsigned char* bufB = (unsigned char*)(ws + O_BUFB);

    // weight prep: single fused launch (also zeroes the DMA scratch)
    hipLaunchKernelGGL(prep_k, dim3(5003), dim3(256), 0, stream,
                       w1, qw1, wf2, qwf2, w2, qwt2, w3, qwt3,
                       w4, qwt4, w5, qwt5, w6, qwt6, wf1, qwf1, zs);

    // conv stack (plane-blocked activations)
    hipLaunchKernelGGL(conv1_k, dim3(2048), dim3(256), 0, stream, x, qw1, g1, b1, bufA);
    hipLaunchKernelGGL((conv_i8_k<64,  64,  32, 32, true,  1, 4>), dim3(512,  1), dim3(256), 0, stream, bufA, qwt2, g2, b2, bufB, zs);
    hipLaunchKernelGGL((conv_i8_k<64,  128, 16, 16, false, 1, 2>), dim3(256,  2), dim3(256), 0, stream, bufB, qwt3, g3, b3, bufA, zs);
    hipLaunchKernelGGL((conv_i8_k<128, 128, 16, 16, true,  1, 1>), dim3(512,  2), dim3(256), 0, stream, bufA, qwt4, g4, b4, bufB, zs);
    hipLaunchKernelGGL((conv_i8_k<128, 256, 8,  8,  false, 4, 1>), dim3(128,  4), dim3(256), 0, stream, bufB, qwt5, g5, b5, bufA, zs);
    hipLaunchKernelGGL((conv_i8_k<256, 256, 8,  8,  true,  4, 1>), dim3(128,  4), dim3(256), 0, stream, bufA, qwt6, g6, b6, bufB, zs);

    // FC head
    hipLaunchKernelGGL(fc1_i8_k, dim3(16, 16), dim3(256), 0, stream, bufB, qwf1, gf1, bf1, bufA);
    hipLaunchKernelGGL(fc2_k, dim3(32), dim3(256), 0, stream, bufA, qwf2, gf2, bf2, (float*)d_out);
}

// Round 8
// 241.228 us; speedup vs baseline: 1.0545x; 1.0545x over previous
//
#include <hip/hip_runtime.h>

// ---------------------------------------------------------------------------
// IntegerCifar10Net: 4-bit quantized CNN, B=512.
// Post-layer-1 math is EXACT integer arithmetic (acts 0..7, weights -7..7,
// partial sums < 2^31) -> i8 MFMA (mfma_i32_16x16x64_i8, exact i32 accum).
// Layer 1 stays fp64 (continuous input; matches ref quant decisions).
//
// Round-11 changes (round-7 post-mortem: fp32 LDS staging = +620 cvt/thread
// in the hot loop -> +9us. Reverted to fp64 operands; removed weight LDS):
//  * conv1 weights: prep emits fp64 qw1d[1728] (exact small ints). conv1
//    reads them via a readfirstlane(cg)-anchored UNIFORM pointer -- the
//    index ((cog*16+cg*4+l)*3+ci)*9+tap is wave-uniform -> scalar s_load
//    through K$: zero VALU, zero LDS, zero cvt. Values bit-identical to
//    round-6 (same doubles, same FMA order) -> bit-exact.
//  * conv1 LDS: xs fp64 (8160) + ob ping-pong (8192) = 16.4 KB; static cap
//    8 blocks/CU (was 5 at 30.2 KB). wd staging loop gone.
//  * fp32 weight prep kept (proven neutral; == reference's own fp32 rounding).
// Inter-layer activations: plane-blocked u8 [img][c/16][px][16] (value=7*act).
// ---------------------------------------------------------------------------

typedef __attribute__((ext_vector_type(4))) int v4i;

#if defined(__has_builtin)
# if __has_builtin(__builtin_amdgcn_sdot4)
#  define HAS_SDOT4 1
# endif
#endif

__device__ __forceinline__ int dot4_i8(int a, int b, int c) {
#ifdef HAS_SDOT4
    return __builtin_amdgcn_sdot4(a, b, c, false);
#else
    c += ((a      ) & 0xff) * (int)(signed char)(b      );
    c += ((a >>  8) & 0xff) * (int)(signed char)(b >>  8);
    c += ((a >> 16) & 0xff) * (int)(signed char)(b >> 16);
    c += ((a >> 24) & 0xff) * (int)(signed char)(b >> 24);
    return c;
#endif
}

// global->LDS 16B DMA (dest must be wave-uniform base + lane*16)
__device__ __forceinline__ void gld_lds16(const void* g, void* l) {
    __builtin_amdgcn_global_load_lds(
        (const __attribute__((address_space(1))) unsigned int*)g,
        (__attribute__((address_space(3))) unsigned int*)l, 16, 0, 0);
}

// workspace offsets (bytes) -- repacked, same 45.2 MB footprint
#define O_QW1D   0u          // 13824   f64 conv1 [64][3][9]
#define O_QWF2   14336u      // 5120    i8 fc2   [10][512]
#define O_ZERO   19456u      // 256     zero scratch for OOB DMA source
#define O_QWT2   24576u      // 36864   i8 [1grp][1pass][4][576][16]
#define O_QWT3   65536u      // 73728   i8 [2grp][1pass][4][576][16]
#define O_QWT4   147456u     // 147456  i8 [2grp][2pass][4][576][16]
#define O_QWT5   294912u     // 294912  i8 [4grp][2pass][4][576][16]
#define O_QWT6   589824u     // 589824  i8 [4grp][4pass][4][576][16]
#define O_QWF1   1179648u    // 2097152 i8 [512][4096] k in plane-blocked order
#define O_BUFA   3276800u    // 33.5 MB
#define O_BUFB   36831232u   // 8.4 MB  (total ~45.2 MB)

// ---------------------------------------------------------------------------
// fused weight prep: one launch, segment-dispatched by blockIdx.x
// fp32 quant == reference's exact op sequence (round-half-even).
// ---------------------------------------------------------------------------
__device__ __forceinline__ signed char quant_wf(float v) {
    return (signed char)(int)rintf(fminf(fmaxf(v, -1.0f), 1.0f) * 7.0f);
}

// conv1 weights -> fp64 (exact small ints)
__device__ __forceinline__ void quantw1_body(const float* __restrict__ w,
                                             double* __restrict__ q, int i, int n) {
    if (i < n) q[i] = (double)quant_wf(w[i]);
}

__device__ __forceinline__ void quantw_body(const float* __restrict__ w,
                                            signed char* __restrict__ q, int i, int n) {
    if (i < n) q[i] = quant_wf(w[i]);
}

// conv weights: fp32 [CO][CI][3][3] -> i8 LDS-image layout
// [grp][pass][c][row=co_l*9+tap][b], co=grp*64+co_l, ci=pass*64+c*16+b
__device__ __forceinline__ void quantw_t8p_body(const float* __restrict__ w,
                                                signed char* __restrict__ o,
                                                int CI, int i, int n) {
    if (i < n) {
        const int b  = i & 15;
        const int t  = i >> 4;              // 16B-chunk index
        const int rows_per_grp = CI * 36;   // (CI/64)*2304
        const int grp  = t / rows_per_grp;
        int rr = t - grp * rows_per_grp;
        const int pass = rr / 2304;
        rr -= pass * 2304;
        const int c    = rr / 576;
        const int row  = rr - c * 576;
        const int co_l = row / 9;
        const int tap  = row - co_l * 9;
        const int co = grp * 64 + co_l;
        const int ci = pass * 64 + c * 16 + b;
        o[i] = quant_wf(w[(co * CI + ci) * 9 + tap]);
    }
}

// fc1 weights, one block per row: fp32 [512][4096 nchw-k] -> i8 plane-blocked
// out kn = gp*256 + px*16 + b  maps to  nchw ko = (gp*16+b)*16 + px.
__device__ __forceinline__ void quantw_fc1_row(const float* __restrict__ w,
                                               signed char* __restrict__ o,
                                               int row, int tid,
                                               unsigned char* __restrict__ sb)
{
    const float4* wr = (const float4*)(w + row * 4096);
    unsigned int* so = (unsigned int*)sb;
#pragma unroll
    for (int k = 0; k < 4; ++k) {
        const int d = k * 256 + tid;           // dword index 0..1023
        float4 v = wr[d];
        unsigned int pk =
              ((unsigned int)(unsigned char)quant_wf(v.x))
            | ((unsigned int)(unsigned char)quant_wf(v.y) << 8)
            | ((unsigned int)(unsigned char)quant_wf(v.z) << 16)
            | ((unsigned int)(unsigned char)quant_wf(v.w) << 24);
        so[d] = pk;
    }
    __syncthreads();
    unsigned int* og = (unsigned int*)(o + row * 4096);
#pragma unroll
    for (int k = 0; k < 4; ++k) {
        const int od = k * 256 + tid;
        unsigned int pk = 0;
#pragma unroll
        for (int u = 0; u < 4; ++u) {
            const int kn = od * 4 + u;
            const int gp = kn >> 8, r = kn & 255;
            const int px = r >> 4, b = r & 15;
            const int ko = (gp * 16 + b) * 16 + px;
            pk |= (unsigned int)sb[ko] << (8 * u);
        }
        og[od] = pk;
    }
}

// block ranges: [0,7) qw1d | [7,27) qwf2 | [27,171) qwt2 | [171,459) qwt3 |
// [459,1035) qwt4 | [1035,2187) qwt5 | [2187,4491) qwt6 | [4491,5003) qwf1
__global__ __launch_bounds__(256) void prep_k(
    const float* __restrict__ w1,  double* __restrict__ qw1d,
    const float* __restrict__ wf2, signed char* __restrict__ qwf2,
    const float* __restrict__ w2,  signed char* __restrict__ qwt2,
    const float* __restrict__ w3,  signed char* __restrict__ qwt3,
    const float* __restrict__ w4,  signed char* __restrict__ qwt4,
    const float* __restrict__ w5,  signed char* __restrict__ qwt5,
    const float* __restrict__ w6,  signed char* __restrict__ qwt6,
    const float* __restrict__ wf1, signed char* __restrict__ qwf1,
    unsigned char* __restrict__ zs)
{
    __shared__ __align__(16) unsigned char sb[4096];
    const int blk = blockIdx.x;
    const int t   = threadIdx.x;
    if (blk == 0 && t < 16) ((int4*)zs)[t] = int4{0, 0, 0, 0};
    if      (blk < 7)    quantw1_body(w1, qw1d, blk * 256 + t, 1728);
    else if (blk < 27)   quantw_body(wf2, qwf2, (blk - 7) * 256 + t, 5120);
    else if (blk < 171)  quantw_t8p_body(w2, qwt2, 64,  (blk - 27)   * 256 + t, 36864);
    else if (blk < 459)  quantw_t8p_body(w3, qwt3, 64,  (blk - 171)  * 256 + t, 73728);
    else if (blk < 1035) quantw_t8p_body(w4, qwt4, 128, (blk - 459)  * 256 + t, 147456);
    else if (blk < 2187) quantw_t8p_body(w5, qwt5, 128, (blk - 1035) * 256 + t, 294912);
    else if (blk < 4491) quantw_t8p_body(w6, qwt6, 256, (blk - 2187) * 256 + t, 589824);
    else                 quantw_fc1_row(wf1, qwf1, blk - 4491, t, sb);
}

// ---------------------------------------------------------------------------
// conv1: 3->64, 32x32, fp64-exact. Output: plane-blocked [img][4][1024][16].
// One block per (img,slab); xs fp64 in LDS; weights read as fp64 through a
// wave-uniform pointer (scalar K$ loads, no LDS, no cvt); cog loop computes
// 16 co at a time; ob ping-pong; contiguous 4KB uint4 stores per cog.
// LDS 16.4 KB -> 8 blocks/CU static (grid = 8/CU).
// ---------------------------------------------------------------------------
#define XSTR 34
#define XPL  (10 * XSTR)
__global__ __launch_bounds__(256) void conv1_k(
    const float* __restrict__ x, const double* __restrict__ wqd,
    const float* __restrict__ gvec, const float* __restrict__ bvec,
    unsigned char* __restrict__ out)
{
    __shared__ double xs[3 * XPL];       // 8160 B: [ci][10 rows][34 cols]
    __shared__ __align__(16) unsigned char ob[2][256 * 16];  // ping-pong 8 KB

    const int tid  = threadIdx.x;
    const int sp   = tid & 63;
    const int cg   = tid >> 6;
    const int img  = blockIdx.x >> 2;
    const int slab = blockIdx.x & 3;
    const int y0s  = slab * 8;
    const int yb = sp >> 4, xb = sp & 15;
    const int ysl = yb * 2, x0 = xb * 2;

    // wave-uniform weight base: cg is constant within a wave
    const int cgu = __builtin_amdgcn_readfirstlane(cg);
    const double* wb = wqd + cgu * 108;   // cg*4 co * 27 taps

    for (int i = tid; i < 3 * XPL; i += 256) {
        int ci = i / XPL, r = i - ci * XPL;
        int ry = r / XSTR, rx = r - ry * XSTR;
        int gy = y0s - 1 + ry, gx = rx - 1;
        double v = 0.0;
        if ((unsigned)gy < 32u && (unsigned)gx < 32u)
            v = (double)x[(img * 3 + ci) * 1024 + gy * 32 + gx];
        xs[i] = v;
    }
    __syncthreads();

    for (int cog = 0; cog < 4; ++cog) {
        double acc[4][4];
#pragma unroll
        for (int l = 0; l < 4; ++l)
#pragma unroll
            for (int p = 0; p < 4; ++p) acc[l][p] = 0.0;

#pragma unroll
        for (int ci = 0; ci < 3; ++ci) {
            double a[4][4];
#pragma unroll
            for (int iy = 0; iy < 4; ++iy)
#pragma unroll
                for (int ix = 0; ix < 4; ++ix)
                    a[iy][ix] = xs[ci * XPL + (ysl + iy) * XSTR + (x0 + ix)];
#pragma unroll
            for (int l = 0; l < 4; ++l) {
                const double* wr = wb + cog * 432 + l * 27 + ci * 9;  // uniform
#pragma unroll
                for (int ky = 0; ky < 3; ++ky)
#pragma unroll
                    for (int kx = 0; kx < 3; ++kx) {
                        const double wv = wr[ky * 3 + kx];
                        acc[l][0] = fma(wv, a[ky    ][kx    ], acc[l][0]);
                        acc[l][1] = fma(wv, a[ky    ][kx + 1], acc[l][1]);
                        acc[l][2] = fma(wv, a[ky + 1][kx    ], acc[l][2]);
                        acc[l][3] = fma(wv, a[ky + 1][kx + 1], acc[l][3]);
                    }
            }
        }

        // epilogue: 7*y = acc*g + 7*b; q = clamp(rint(7y), 0, 7)
        int qv[4][4];
#pragma unroll
        for (int l = 0; l < 4; ++l) {
            const int co = cog * 16 + cg * 4 + l;
            const double gg  = (double)gvec[co];
            const double bb7 = (double)bvec[co] * 7.0;
#pragma unroll
            for (int p = 0; p < 4; ++p) {
                int qi = (int)rint(fma(acc[l][p], gg, bb7));
                qv[l][p] = qi < 0 ? 0 : (qi > 7 ? 7 : qi);
            }
        }
#pragma unroll
        for (int p = 0; p < 4; ++p) {
            unsigned int wv = (unsigned int)qv[0][p]
                            | ((unsigned int)qv[1][p] << 8)
                            | ((unsigned int)qv[2][p] << 16)
                            | ((unsigned int)qv[3][p] << 24);
            const int r = ysl + (p >> 1), c = x0 + (p & 1);
            const int px = r * 32 + c;
            const int slot = (cg ^ ((px >> 3) & 3) ^ ((px >> 6) & 3)) & 3;
            *(unsigned int*)&ob[cog & 1][px * 16 + slot * 4] = wv;
        }
        __syncthreads();
        {
            uint4 d = *(const uint4*)&ob[cog & 1][tid * 16];
            const int s = (((tid >> 3) & 3) ^ ((tid >> 6) & 3)) & 3;
            unsigned e0 = d.x, e1 = d.y, e2 = d.z, e3 = d.w, t;
            if (s & 1) { t = e0; e0 = e1; e1 = t; t = e2; e2 = e3; e3 = t; }
            if (s & 2) { t = e0; e0 = e2; e2 = t; t = e1; e1 = e3; e3 = t; }
            uint4 o; o.x = e0; o.y = e1; o.z = e2; o.w = e3;
            *(uint4*)&out[(size_t)img * 65536 + (size_t)cog * 16384
                          + y0s * 512 + tid * 16] = o;
        }
    }
}

// ---------------------------------------------------------------------------
// i8 MFMA implicit-GEMM conv: plane-blocked u8 in [img][CI/16][H*W][16],
// pre-permuted i8 weights, plane-blocked u8 out [img][CO/16][PXO][16].
// Block: 256 thr = 4 waves; 64 co x 256 px. K in ci-chunks of 64.
// All staging via global_load_lds width-16 DMA (lane-stride 16B = dense).
// TPB>1 (NPASS==1, IPB==1): persistent weights + DOUBLE-BUFFERED act tiles.
// Morton px->m: lane's 4 accs = 2x2 pool window.
// Epilogue: division-free fp64 affine; POOL maxes INTEGER accs first (g>0).
// ---------------------------------------------------------------------------
template<int CI, int CO, int H, int W, bool POOL, int IPB, int TPB>
__global__ __launch_bounds__(256, 2) void conv_i8_k(
    const unsigned char* __restrict__ in, const signed char* __restrict__ wt,
    const float* __restrict__ gvec, const float* __restrict__ bvec,
    unsigned char* __restrict__ out, const unsigned char* __restrict__ zs)
{
    constexpr int ATX    = (IPB == 1) ? 18 : 10;
    constexpr int APX    = ATX * ATX;
    constexpr int APLANE = IPB * APX * 16;       // bytes per act plane
    constexpr int AREG   = 4 * APLANE;           // one act buffer
    constexpr int NBUF   = (TPB > 1) ? 2 : 1;
    constexpr int WBASE  = NBUF * AREG;
    constexpr int WPLANE = 576 * 16;             // 64 co x 9 taps rows
    constexpr int NPASS  = CI / 64;
    constexpr int PIN    = CI / 16;              // input planes
    constexpr int PXI    = H * W;                // input px per img
    constexpr int POUT   = CO / 16;
    constexpr int PXO    = POOL ? (H / 2) * (W / 2) : H * W;
    static_assert(TPB == 1 || (NPASS == 1 && IPB == 1), "TPB>1 needs NPASS==1");

    __shared__ __align__(16) char lds[WBASE + 4 * WPLANE];

    const int tid = threadIdx.x;
    const int l   = tid & 63;
    const int w   = tid >> 6;
    const int n   = l & 15;
    const int q   = l >> 4;

    const int co_base = blockIdx.y * 64;
    const int wy8 = (IPB == 1) ? (w >> 1) * 8 : 0;
    const int wx8 = (IPB == 1) ? (w & 1) * 8 : 0;
    const int tilepx = (IPB == 4) ? w * APX : 0;

    const int ly = ((n >> 3) & 1) * 2 + ((n >> 1) & 1);
    const int lx = ((n >> 2) & 1) * 2 + (n & 1);

    int abase[4], wbase[4];
#pragma unroll
    for (int ps = 0; ps < 4; ++ps) {
        int ay0 = wy8 + (ps >> 1) * 4 + ly;
        int ax0 = wx8 + (ps & 1) * 4 + lx;
        abase[ps] = q * APLANE + (tilepx + ay0 * ATX + ax0) * 16;
    }
#pragma unroll
    for (int cs = 0; cs < 4; ++cs)
        wbase[cs] = WBASE + q * WPLANE + ((cs * 16 + n) * 9) * 16;

    // --- staging helpers (plane-blocked global layout) ---
    auto stage_act = [&](int boff, int img0, int regY0, int regX0, int pass) {
#pragma unroll
        for (int c = 0; c < 4; ++c) {
            const int gp = pass * 4 + c;
            for (int base = 0; base < IPB * APX; base += 256) {
                const int px_g = base + tid;
                if (px_g < IPB * APX) {
                    int tile = 0, px = px_g;
                    if (IPB == 4) { tile = px_g / APX; px = px_g - tile * APX; }
                    const int gy = regY0 - 1 + px / ATX;
                    const int gx = regX0 - 1 + px % ATX;
                    const int bimg = img0 + tile;
                    const void* src =
                        ((unsigned)gy < (unsigned)H && (unsigned)gx < (unsigned)W)
                        ? (const void*)&in[((size_t)(bimg * PIN + gp) * PXI + gy * W + gx) * 16]
                        : (const void*)zs;
                    gld_lds16(src, &lds[boff + c * APLANE + px_g * 16]);
                }
            }
        }
    };
    auto stage_w = [&](int pass) {
        const signed char* wsrc = wt + (size_t)(blockIdx.y * NPASS + pass) * (4 * WPLANE);
#pragma unroll
        for (int base = 0; base < 2304; base += 256)
            gld_lds16(wsrc + (base + tid) * 16, &lds[WBASE + (base + tid) * 16]);
    };
    auto taps = [&](v4i acc[4][4], int boff) {
#pragma unroll
        for (int tap = 0; tap < 9; ++tap) {
            const int toff = ((tap / 3) * ATX + (tap % 3)) * 16;
            v4i bf[4], af[4];
#pragma unroll
            for (int cs = 0; cs < 4; ++cs)
                bf[cs] = *(const v4i*)&lds[wbase[cs] + tap * 16];
#pragma unroll
            for (int ps = 0; ps < 4; ++ps)
                af[ps] = *(const v4i*)&lds[boff + abase[ps] + toff];
#pragma unroll
            for (int ps = 0; ps < 4; ++ps)
#pragma unroll
                for (int cs = 0; cs < 4; ++cs)
                    acc[ps][cs] = __builtin_amdgcn_mfma_i32_16x16x64_i8(
                        af[ps], bf[cs], acc[ps][cs], 0, 0, 0);
        }
    };
    auto epilogue = [&](v4i acc[4][4], int img0, int regY0, int regX0) {
        const int bimg = (IPB == 1) ? img0 : (img0 + w);
#pragma unroll
        for (int cs = 0; cs < 4; ++cs) {
            const int co = co_base + cs * 16 + n;
            const int pl = (co_base >> 4) + cs;
            const double g7 = (double)gvec[co] * (1.0 / 7.0);
            const double b7 = (double)bvec[co] * 7.0;
#pragma unroll
            for (int ps = 0; ps < 4; ++ps) {
                const int Yb = regY0 + wy8 + (ps >> 1) * 4 + (q >> 1) * 2;
                const int Xb = regX0 + wx8 + (ps & 1) * 4 + (q & 1) * 2;
                if (POOL) {
                    int ms = max(max(acc[ps][cs][0], acc[ps][cs][1]),
                                 max(acc[ps][cs][2], acc[ps][cs][3]));
                    int qi = (int)rint(fma((double)ms, g7, b7));
                    qi = qi < 0 ? 0 : (qi > 7 ? 7 : qi);
                    out[((size_t)(bimg * POUT + pl) * PXO + (Yb >> 1) * (W / 2) + (Xb >> 1)) * 16 + n]
                        = (unsigned char)qi;
                } else {
#pragma unroll
                    for (int r = 0; r < 4; ++r) {
                        int qi = (int)rint(fma((double)acc[ps][cs][r], g7, b7));
                        qi = qi < 0 ? 0 : (qi > 7 ? 7 : qi);
                        const int Y = Yb + (r >> 1), X = Xb + (r & 1);
                        out[((size_t)(bimg * POUT + pl) * PXO + Y * W + X) * 16 + n]
                            = (unsigned char)qi;
                    }
                }
            }
        }
    };

    if (TPB == 1) {
        // ---- pass loop, weights re-staged per pass ----
        int img = 0, regY0 = 0, regX0 = 0;
        if (IPB == 1) {
            constexpr int rpw = W / 16;
            constexpr int rpi = (H / 16) * rpw;
            img   = blockIdx.x / rpi;
            int r = blockIdx.x % rpi;
            regY0 = (r / rpw) * 16;
            regX0 = (r % rpw) * 16;
        } else {
            img = (int)blockIdx.x * 4;
        }
        v4i acc[4][4];
#pragma unroll
        for (int ps = 0; ps < 4; ++ps)
#pragma unroll
            for (int cs = 0; cs < 4; ++cs) acc[ps][cs] = (v4i)0;

        for (int pass = 0; pass < NPASS; ++pass) {
            __syncthreads();
            stage_act(0, img, regY0, regX0, pass);
            stage_w(pass);
            __syncthreads();
            taps(acc, 0);
        }
        epilogue(acc, img, regY0, regX0);
    } else {
        // ---- persistent weights + double-buffered act tile pipeline ----
        auto tilec = [&](int t, int& im, int& ry, int& rx) {
            if (H == 32) { im = t >> 2; ry = ((t >> 1) & 1) * 16; rx = (t & 1) * 16; }
            else         { im = t; ry = 0; rx = 0; }
        };
        stage_w(0);
        int im0, ry0, rx0;
        tilec((int)blockIdx.x * TPB, im0, ry0, rx0);
        stage_act(0, im0, ry0, rx0, 0);
        __syncthreads();
        for (int tt = 0; tt < TPB; ++tt) {
            int imc, ryc, rxc;
            tilec((int)blockIdx.x * TPB + tt, imc, ryc, rxc);
            if (tt + 1 < TPB) {
                int imn, ryn, rxn;
                tilec((int)blockIdx.x * TPB + tt + 1, imn, ryn, rxn);
                stage_act(((tt + 1) & 1) * AREG, imn, ryn, rxn, 0);
            }
            v4i acc[4][4];
#pragma unroll
            for (int ps = 0; ps < 4; ++ps)
#pragma unroll
                for (int cs = 0; cs < 4; ++cs) acc[ps][cs] = (v4i)0;
            taps(acc, (tt & 1) * AREG);
            epilogue(acc, imc, ryc, rxc);
            __syncthreads();   // drains tile t+1's DMA; WAR-safe buffer reuse
        }
    }
}

// ---------------------------------------------------------------------------
// FC1: h[512][4096] u8 x wt[512][4096] i8 -> u8 [512][512], i8 MFMA,
// 32x32 output tile, 4 waves split K=4096 into 1024 each, LDS reduce.
// ---------------------------------------------------------------------------
__global__ __launch_bounds__(256, 2) void fc1_i8_k(
    const unsigned char* __restrict__ h, const signed char* __restrict__ wt,
    const float* __restrict__ gvec, const float* __restrict__ bvec,
    unsigned char* __restrict__ out)
{
    __shared__ int red[4096];
    const int tid = threadIdx.x;
    const int l = tid & 63, w = tid >> 6;
    const int n = l & 15, q = l >> 4;
    const int m0 = blockIdx.x * 32, n0 = blockIdx.y * 32;

    v4i acc[2][2];
#pragma unroll
    for (int a = 0; a < 2; ++a)
#pragma unroll
        for (int b = 0; b < 2; ++b) acc[a][b] = (v4i)0;

    const int kb = w * 1024;
    for (int ks = 0; ks < 16; ++ks) {
        const int k = kb + ks * 64 + q * 16;
        v4i af[2], bf[2];
#pragma unroll
        for (int ms = 0; ms < 2; ++ms)
            af[ms] = *(const v4i*)&h[(m0 + ms * 16 + n) * 4096 + k];
#pragma unroll
        for (int ns = 0; ns < 2; ++ns)
            bf[ns] = *(const v4i*)&wt[(n0 + ns * 16 + n) * 4096 + k];
#pragma unroll
        for (int ms = 0; ms < 2; ++ms)
#pragma unroll
            for (int ns = 0; ns < 2; ++ns)
                acc[ms][ns] = __builtin_amdgcn_mfma_i32_16x16x64_i8(
                    af[ms], bf[ns], acc[ms][ns], 0, 0, 0);
    }

#pragma unroll
    for (int ms = 0; ms < 2; ++ms)
#pragma unroll
        for (int ns = 0; ns < 2; ++ns)
#pragma unroll
            for (int r = 0; r < 4; ++r)
                red[w * 1024 + (ms * 16 + q * 4 + r) * 32 + ns * 16 + n] = acc[ms][ns][r];
    __syncthreads();

#pragma unroll
    for (int j = 0; j < 4; ++j) {
        const int e = tid * 4 + j;
        int s = red[e] + red[1024 + e] + red[2048 + e] + red[3072 + e];
        const int ml = e >> 5, nl = e & 31;
        const int co = n0 + nl;
        double y7 = fma((double)s, (double)gvec[co] * (1.0 / 7.0), (double)bvec[co] * 7.0);
        int qi = (int)rint(y7);
        qi = qi < 0 ? 0 : (qi > 7 ? 7 : qi);
        out[(m0 + ml) * 512 + co] = (unsigned char)qi;
    }
}

// FC2: vectorized int4 loads + dot4
__global__ __launch_bounds__(256) void fc2_k(
    const unsigned char* __restrict__ h, const signed char* __restrict__ wq,
    const float* __restrict__ gvec, const float* __restrict__ bvec,
    float* __restrict__ out)
{
    const int gid = blockIdx.x * 256 + threadIdx.x;
    const int b = gid >> 4;
    const int n = gid & 15;
    if (b >= 512 || n >= 10) return;
    const int* hp = (const int*)&h[b * 512];
    const int* wp = (const int*)&wq[n * 512];
    int s = 0;
#pragma unroll 4
    for (int k = 0; k < 128; k += 4) {
        int4 hv = *(const int4*)&hp[k];
        int4 wv = *(const int4*)&wp[k];
        s = dot4_i8(hv.x, wv.x, s);
        s = dot4_i8(hv.y, wv.y, s);
        s = dot4_i8(hv.z, wv.z, s);
        s = dot4_i8(hv.w, wv.w, s);
    }
    double y7 = fma((double)s, (double)gvec[n] * (1.0 / 7.0), (double)bvec[n] * 7.0);
    double r = rint(y7);
    r = fmin(fmax(r, -7.0), 7.0);
    out[b * 10 + n] = (float)(r / 7.0);
}

// ---------------------------------------------------------------------------
extern "C" void kernel_launch(void* const* d_in, const int* in_sizes, int n_in,
                              void* d_out, int out_size, void* d_ws, size_t ws_size,
                              hipStream_t stream) {
    const float* x   = (const float*)d_in[0];
    const float* w1  = (const float*)d_in[1];
    const float* g1  = (const float*)d_in[2];
    const float* b1  = (const float*)d_in[3];
    const float* w2  = (const float*)d_in[4];
    const float* g2  = (const float*)d_in[5];
    const float* b2  = (const float*)d_in[6];
    const float* w3  = (const float*)d_in[7];
    const float* g3  = (const float*)d_in[8];
    const float* b3  = (const float*)d_in[9];
    const float* w4  = (const float*)d_in[10];
    const float* g4  = (const float*)d_in[11];
    const float* b4  = (const float*)d_in[12];
    const float* w5  = (const float*)d_in[13];
    const float* g5  = (const float*)d_in[14];
    const float* b5  = (const float*)d_in[15];
    const float* w6  = (const float*)d_in[16];
    const float* g6  = (const float*)d_in[17];
    const float* b6  = (const float*)d_in[18];
    const float* wf1 = (const float*)d_in[19];
    const float* gf1 = (const float*)d_in[20];
    const float* bf1 = (const float*)d_in[21];
    const float* wf2 = (const float*)d_in[22];
    const float* gf2 = (const float*)d_in[23];
    const float* bf2 = (const float*)d_in[24];

    char* ws = (char*)d_ws;
    double*        qw1d = (double*)(ws + O_QW1D);
    signed char*   qwf2 = (signed char*)(ws + O_QWF2);
    unsigned char* zs   = (unsigned char*)(ws + O_ZERO);
    signed char*   qwt2 = (signed char*)(ws + O_QWT2);
    signed char*   qwt3 = (signed char*)(ws + O_QWT3);
    signed char*   qwt4 = (signed char*)(ws + O_QWT4);
    signed char*   qwt5 = (signed char*)(ws + O_QWT5);
    signed char*   qwt6 = (signed char*)(ws + O_QWT6);
    signed char*   qwf1 = (signed char*)(ws + O_QWF1);
    unsigned char* bufA = (unsigned char*)(ws + O_BUFA);
    unsigned char* bufB = (unsigned char*)(ws + O_BUFB);

    // weight prep: single fused launch (also zeroes the DMA scratch)
    hipLaunchKernelGGL(prep_k, dim3(5003), dim3(256), 0, stream,
                       w1, qw1d, wf2, qwf2, w2, qwt2, w3, qwt3,
                       w4, qwt4, w5, qwt5, w6, qwt6, wf1, qwf1, zs);

    // conv stack (plane-blocked activations)
    hipLaunchKernelGGL(conv1_k, dim3(2048), dim3(256), 0, stream, x, qw1d, g1, b1, bufA);
    hipLaunchKernelGGL((conv_i8_k<64,  64,  32, 32, true,  1, 4>), dim3(512,  1), dim3(256), 0, stream, bufA, qwt2, g2, b2, bufB, zs);
    hipLaunchKernelGGL((conv_i8_k<64,  128, 16, 16, false, 1, 2>), dim3(256,  2), dim3(256), 0, stream, bufB, qwt3, g3, b3, bufA, zs);
    hipLaunchKernelGGL((conv_i8_k<128, 128, 16, 16, true,  1, 1>), dim3(512,  2), dim3(256), 0, stream, bufA, qwt4, g4, b4, bufB, zs);
    hipLaunchKernelGGL((conv_i8_k<128, 256, 8,  8,  false, 4, 1>), dim3(128,  4), dim3(256), 0, stream, bufB, qwt5, g5, b5, bufA, zs);
    hipLaunchKernelGGL((conv_i8_k<256, 256, 8,  8,  true,  4, 1>), dim3(128,  4), dim3(256), 0, stream, bufA, qwt6, g6, b6, bufB, zs);

    // FC head
    hipLaunchKernelGGL(fc1_i8_k, dim3(16, 16), dim3(256), 0, stream, bufB, qwf1, gf1, bf1, bufA);
    hipLaunchKernelGGL(fc2_k, dim3(32), dim3(256), 0, stream, bufA, qwf2, gf2, bf2, (float*)d_out);
}